// Round 15
// baseline (313.346 us; speedup 1.0000x reference)
//
#include <hip/hip_runtime.h>
#include <hip/hip_bf16.h>

typedef __attribute__((ext_vector_type(4))) float f32x4;
typedef __attribute__((ext_vector_type(8))) short s16x8;

#define B_ 64
#define T_ 4096
#define H_ 512
#define E_ 512
#define BM 128         // T-rows per k2 block (= context chunk)
#define NCH (T_ / BM)  // 32 chunks per batch row

__device__ __forceinline__ short b2s(float x) {
  __hip_bfloat16 h = __float2bfloat16(x);  // RNE; pairs fuse to v_cvt_pk_bf16_f32
  return __builtin_bit_cast(short, h);
}

__device__ __forceinline__ s16x8 cvt8(f32x4 a, f32x4 b) {
  s16x8 r;
  r[0] = b2s(a[0]); r[1] = b2s(a[1]); r[2] = b2s(a[2]); r[3] = b2s(a[3]);
  r[4] = b2s(b[0]); r[5] = b2s(b[1]); r[6] = b2s(b[2]); r[7] = b2s(b[3]);
  return r;
}

__device__ __forceinline__ float bf2f(short s) {
  return __uint_as_float(((unsigned)(unsigned short)s) << 16);
}

__device__ __forceinline__ float fast_tanh(float x) {
  float e;
  asm("v_exp_f32 %0, %1" : "=v"(e) : "v"(x * 2.88539008177792681f));  // 2^(2x/ln2)
  float r;
  asm("v_rcp_f32 %0, %1" : "=v"(r) : "v"(e + 1.0f));
  return 1.0f - 2.0f * r;
}

// k0: fragment-major repack of W_e (rows 512..1023 of W_attn):
// frag(h16, s) is ONE contiguous 1-KiB block; lane i loads base+i*16B.
__global__ __launch_bounds__(512) void k0_fragpack(const float* __restrict__ W,
                                                   unsigned short* __restrict__ WtF) {
  const int h16 = blockIdx.x;   // 0..31
  const int s = blockIdx.y;     // 0..15
  const int tid = threadIdx.x;  // 0..511
  const int lane = tid >> 3, e = tid & 7;
  const int lr = lane & 15, lq = lane >> 4;
  const int k = s * 32 + lq * 8 + e;
  const int h = h16 * 16 + lr;
  WtF[(size_t)(h16 * 16 + s) * 512 + tid] =
      (unsigned short)b2s(W[(size_t)(512 + k) * H_ + h]);
}

// k1: projb[b][h] = b_attn[h] + sum_e hidden[b][e] * W_attn[e][h]
__global__ __launch_bounds__(512) void k1_projb(const float* __restrict__ hidden,
                                                const float* __restrict__ W,
                                                const float* __restrict__ b_attn,
                                                float* __restrict__ projb) {
  __shared__ float hid_s[H_];
  __shared__ float part[4][128];
  const int b = blockIdx.x, hg = blockIdx.y;
  const int tid = threadIdx.x;
  const int hl = tid & 127, es = tid >> 7;
  hid_s[tid] = hidden[b * H_ + tid];
  __syncthreads();
  const int h = hg * 128 + hl;
  const float* wp = W + (size_t)(es * 128) * H_ + h;
  float s = 0.0f;
  #pragma unroll 8
  for (int e = 0; e < 128; ++e) s = fmaf(hid_s[es * 128 + e], wp[(size_t)e * H_], s);
  part[es][hl] = s;
  __syncthreads();
  if (es == 0)
    projb[b * H_ + h] = b_attn[h] + part[0][hl] + part[1][hl] + part[2][hl] + part[3][hl];
}

// k2: fused logits + chunk-softmax + partial context.
// 512 thr = 8 waves (2T x 4H); block = 128T x 512H; wave tile 64T x 128H,
// acc[4][8]=128 AGPR. BM=128 HALVES per-CU B traffic (32 KB/step, 1 block/CU).
// QUARTER-INTERLEAVED fill: prologue converts K-chunks 0..15 only; batches
// 0..11 (chunks 16..63, 4 chunks each) load at step n / ds_write at step n+1
// (parity reg pairs), 3 in-loop barriers at tops of steps 4/8/12 (after the
// quarter's last write). Otherwise zero-barrier drift loop; B from
// fragment-major WtF (coalesced 1-KiB frags), reg ping-pong; single aCur.
// Epilogue context reads the bf16 A tile from LDS.
__global__ __launch_bounds__(512, 2) void k2_logits(
    const float* __restrict__ enc, const unsigned short* __restrict__ wtF,
    const float* __restrict__ projb, const float* __restrict__ vw,
    float* __restrict__ logits, float* __restrict__ mstat,
    float* __restrict__ partial) {
  __shared__ unsigned short a_s[BM * 512];  // 128 KiB, whole-K A tile (bf16)
  __shared__ float projb_s[H_];
  __shared__ float vw_s[H_];
  __shared__ float part[BM][4];
  __shared__ float lg_s[BM];
  __shared__ float comb[7][64][8];  // 14 KiB, context combine

  const int b = blockIdx.y;
  const int chunk = blockIdx.x;
  const int t0 = chunk * BM;
  const int tid = threadIdx.x;
  const int lane = tid & 63;
  const int w = tid >> 6;    // 0..7
  const int waveT = w >> 2;  // 0..1  (T half)
  const int waveH = w & 3;   // 0..3  (H slice)
  const int lr = lane & 15;
  const int lq = lane >> 4;

  projb_s[tid] = projb[b * H_ + tid];
  vw_s[tid] = vw[tid];

  const size_t row0 = (size_t)b * T_ + t0;

  // fill geometry: thread owns (row ra, slot ca); chunk = 16 B of bf16
  const int ra = tid >> 2, ca = tid & 3;  // ra 0..127
  const float* aSrc = enc + (row0 + ra) * (size_t)E_;
  unsigned short* aRow = &a_s[ra * 512];

  // ---- prologue: direct-fill quarter 0 (chunks 0..15) ----
  {
    f32x4 g[8];
    #pragma unroll
    for (int j = 0; j < 4; ++j) {
      const int c = ca + 4 * j;
      g[2 * j] = *(const f32x4*)(aSrc + c * 8);
      g[2 * j + 1] = *(const f32x4*)(aSrc + c * 8 + 4);
    }
    #pragma unroll
    for (int j = 0; j < 4; ++j) {
      const int c = ca + 4 * j;
      *(s16x8*)&aRow[(c ^ (ra & 7)) * 8] = cvt8(g[2 * j], g[2 * j + 1]);
    }
  }

  const int whu = __builtin_amdgcn_readfirstlane(waveH);
  const unsigned short* wtW = wtF + ((size_t)whu * 8 * 16) * 512 + (size_t)lane * 8;
  const unsigned short* aBase = &a_s[0];

#define LOADB(dst, s)                                                        \
  _Pragma("unroll") for (int nb = 0; nb < 8; ++nb) dst[nb] =                 \
      *(const s16x8*)(wtW + ((size_t)(nb * 16 + (s)) << 9));
#define LOADA(dst, s)                                                        \
  _Pragma("unroll") for (int a = 0; a < 4; ++a) dst[a] =                     \
      *(const s16x8*)&aBase[(waveT * 64 + a * 16 + lr) * 512 +               \
                            (((s) * 4 + lq) ^ (lr & 7)) * 8];
#define MFMA32(af, bf)                                                       \
  __builtin_amdgcn_s_setprio(1);                                             \
  _Pragma("unroll") for (int a = 0; a < 4; ++a)                              \
  _Pragma("unroll") for (int nb = 0; nb < 8; ++nb) acc[a][nb] =              \
      __builtin_amdgcn_mfma_f32_16x16x32_bf16(af[a], bf[nb], acc[a][nb], 0, 0, 0); \
  __builtin_amdgcn_s_setprio(0);
// batch n (0..11) <-> chunks 16 + 4n + ca
#define LDFILL(dst, n)                                                       \
  {                                                                          \
    const int c_ = 16 + (n)*4 + ca;                                          \
    dst##0 = *(const f32x4*)(aSrc + c_ * 8);                                 \
    dst##1 = *(const f32x4*)(aSrc + c_ * 8 + 4);                             \
  }
#define WRFILL(src, n)                                                       \
  {                                                                          \
    const int c_ = 16 + (n)*4 + ca;                                          \
    *(s16x8*)&aRow[(c_ ^ (ra & 7)) * 8] = cvt8(src##0, src##1);              \
  }
#define QBARRIER                                                             \
  asm volatile("s_waitcnt lgkmcnt(0)" ::: "memory");                         \
  __builtin_amdgcn_s_barrier();                                              \
  __builtin_amdgcn_sched_barrier(0);

  f32x4 acc[4][8] = {};
  s16x8 bA[8], bB[8], aCur[4];
  f32x4 fE0, fE1, fO0, fO1;  // parity fill-reg pairs

  LOADB(bA, 0);
  __syncthreads();  // quarter 0 visible

  #pragma unroll
  for (int p = 0; p < 8; ++p) {
    const int s = 2 * p;
    // ======== even step s ========
    if (s < 12) LDFILL(fE, s);          // batch s (even -> fE)
    if (s >= 2 && s <= 12) WRFILL(fO, s - 1);  // batch s-1 (odd -> fO)
    if (s == 4 || s == 8 || s == 12) { QBARRIER }  // quarter s/4 now readable
    LOADB(bB, s + 1);
    LOADA(aCur, s);
    MFMA32(aCur, bA);
    // ======== odd step s+1 ========
    if (s + 1 < 12) LDFILL(fO, s + 1);  // batch s+1 (odd -> fO)
    if (s < 12) WRFILL(fE, s);          // batch s (even -> fE)
    if (p < 7) LOADB(bA, s + 2);
    LOADA(aCur, s + 1);
    MFMA32(aCur, bB);
  }
#undef LOADA
#undef LOADB
#undef MFMA32
#undef LDFILL
#undef WRFILL
#undef QBARRIER

  // ---- logits: energy = tanh(acc + projb), partial = sum_h energy * vw ----
  #pragma unroll
  for (int a = 0; a < 4; ++a) {
    #pragma unroll
    for (int j = 0; j < 4; ++j) {
      float ssum = 0.0f;
      #pragma unroll
      for (int nb = 0; nb < 8; ++nb) {
        const int h = waveH * 128 + nb * 16 + lr;  // C/D: col = lane&15
        float x = acc[a][nb][j] + projb_s[h];
        ssum += fast_tanh(x) * vw_s[h];
      }
      ssum += __shfl_xor(ssum, 1);
      ssum += __shfl_xor(ssum, 2);
      ssum += __shfl_xor(ssum, 4);
      ssum += __shfl_xor(ssum, 8);
      if (lr == 0) part[waveT * 64 + a * 16 + lq * 4 + j][waveH] = ssum;
    }
  }
  __syncthreads();
  if (tid < BM) {
    float l = part[tid][0] + part[tid][1] + part[tid][2] + part[tid][3];
    lg_s[tid] = l;
    logits[(size_t)b * T_ + t0 + tid] = l;
  }
  __syncthreads();

  // ---- chunk softmax numerator + partial context from LDS bf16 A tile ----
  float m_c = -1e30f;
  #pragma unroll 8
  for (int t = 0; t < BM; ++t) m_c = fmaxf(m_c, lg_s[t]);

  const int cc = tid & 63;  // bf16 chunk column (8 e-values)
  const int tg = tid >> 6;  // 0..7, 16 t-rows each
  float a8[8] = {};
  #pragma unroll 4
  for (int i = 0; i < 16; ++i) {
    const int r = tg * 16 + i;
    float pw = __expf(lg_s[r] - m_c);
    s16x8 av = *(const s16x8*)&a_s[r * 512 + (cc ^ (r & 7)) * 8];
    #pragma unroll
    for (int e = 0; e < 8; ++e) a8[e] = fmaf(pw, bf2f(av[e]), a8[e]);
  }
  if (tg > 0) {
    #pragma unroll
    for (int e = 0; e < 8; ++e) comb[tg - 1][cc][e] = a8[e];
  }
  __syncthreads();
  if (tg == 0) {
    float* pp = partial + ((size_t)(b * NCH + chunk)) * E_ + cc * 8;
    #pragma unroll
    for (int e = 0; e < 8; ++e) {
      float v = a8[e];
      #pragma unroll
      for (int g = 0; g < 7; ++g) v += comb[g][cc][e];
      pp[e] = v;
    }
    if (tid == 0) mstat[b * NCH + chunk] = m_c;
  }
}

// k3: softmax over T per batch -> weights; also per-b (max, Z)
__global__ __launch_bounds__(256) void k3_softmax(const float* __restrict__ logits,
                                                  float* __restrict__ weights,
                                                  float* __restrict__ mz) {
  __shared__ float red[4];
  const int b = blockIdx.x;
  const int tid = threadIdx.x;
  const float* lg = logits + (size_t)b * T_;
  float v[16];
  float m = -1e30f;
  #pragma unroll
  for (int i = 0; i < 16; ++i) {
    v[i] = lg[tid + i * 256];
    m = fmaxf(m, v[i]);
  }
  #pragma unroll
  for (int d = 1; d < 64; d <<= 1) m = fmaxf(m, __shfl_xor(m, d));
  if ((tid & 63) == 0) red[tid >> 6] = m;
  __syncthreads();
  m = fmaxf(fmaxf(red[0], red[1]), fmaxf(red[2], red[3]));
  __syncthreads();
  float s = 0.0f;
  #pragma unroll
  for (int i = 0; i < 16; ++i) {
    v[i] = __expf(v[i] - m);
    s += v[i];
  }
  #pragma unroll
  for (int d = 1; d < 64; d <<= 1) s += __shfl_xor(s, d);
  if ((tid & 63) == 0) red[tid >> 6] = s;
  __syncthreads();
  s = red[0] + red[1] + red[2] + red[3];
  float inv = 1.0f / s;
  #pragma unroll
  for (int i = 0; i < 16; ++i) weights[(size_t)b * T_ + tid + i * 256] = v[i] * inv;
  if (tid == 0) {
    mz[b * 2] = m;
    mz[b * 2 + 1] = s;
  }
}

// k5: context = sum_c exp(m_c - m_b) * partial[b,c,:] / Z_b
__global__ __launch_bounds__(128) void k5_ctx_final(const float* __restrict__ partial,
                                                    const float* __restrict__ mstat,
                                                    const float* __restrict__ mz,
                                                    float* __restrict__ ctx) {
  __shared__ float sc[NCH];
  const int b = blockIdx.x;
  const int tid = threadIdx.x;
  const float m_b = mz[b * 2];
  const float invZ = 1.0f / mz[b * 2 + 1];
  if (tid < NCH) sc[tid] = __expf(mstat[b * NCH + tid] - m_b);
  __syncthreads();
  const float* pp = partial + (size_t)b * NCH * E_ + tid * 4;
  f32x4 s = {};
  #pragma unroll 8
  for (int c = 0; c < NCH; ++c) s += sc[c] * (*(const f32x4*)(pp + (size_t)c * E_));
  s *= invZ;
  *(f32x4*)(ctx + (size_t)b * E_ + tid * 4) = s;
}

extern "C" void kernel_launch(void* const* d_in, const int* in_sizes, int n_in,
                              void* d_out, int out_size, void* d_ws, size_t ws_size,
                              hipStream_t stream) {
  const float* hidden = (const float*)d_in[0];
  const float* enc = (const float*)d_in[1];
  const float* W_attn = (const float*)d_in[2];
  const float* b_attn = (const float*)d_in[3];
  const float* v_w = (const float*)d_in[4];

  float* out_ctx = (float*)d_out;                  // 64*512
  float* out_w = (float*)d_out + (size_t)B_ * H_;  // 64*4096

  char* ws = (char*)d_ws;
  unsigned short* WtF = (unsigned short*)ws;     // 512 KiB (fragment-major)
  float* projb = (float*)(ws + (512 << 10));     // 128 KiB
  float* logits = (float*)(ws + (640 << 10));    // 1 MiB
  float* mstat = (float*)(ws + (1664 << 10));    // 8 KiB (64*32 chunk maxes)
  float* mz = (float*)(ws + (1700 << 10));       // 512 B  (per-b max, Z)
  float* partial = (float*)(ws + (1728 << 10));  // 4 MiB  (64*32*512 fp32)

  k0_fragpack<<<dim3(32, 16), 512, 0, stream>>>(W_attn, WtF);
  k1_projb<<<dim3(64, 4), 512, 0, stream>>>(hidden, W_attn, b_attn, projb);
  k2_logits<<<dim3(NCH, B_), 512, 0, stream>>>(enc, WtF, projb, v_w, logits, mstat, partial);
  k3_softmax<<<B_, 256, 0, stream>>>(logits, out_w, mz);
  k5_ctx_final<<<B_, 128, 0, stream>>>(partial, mstat, mz, out_ctx);
}

// Round 16
// 227.387 us; speedup vs baseline: 1.3780x; 1.3780x over previous
//
#include <hip/hip_runtime.h>
#include <hip/hip_bf16.h>

typedef __attribute__((ext_vector_type(4))) float f32x4;
typedef __attribute__((ext_vector_type(8))) short s16x8;

#define B_ 64
#define T_ 4096
#define H_ 512
#define E_ 512
#define BM 64          // T-rows per k2 block (= context chunk)
#define NCH (T_ / BM)  // 64 chunks per batch row

__device__ __forceinline__ short b2s(float x) {
  __hip_bfloat16 h = __float2bfloat16(x);  // RNE; pairs fuse to v_cvt_pk_bf16_f32
  return __builtin_bit_cast(short, h);
}

__device__ __forceinline__ s16x8 cvt8(f32x4 a, f32x4 b) {
  s16x8 r;
  r[0] = b2s(a[0]); r[1] = b2s(a[1]); r[2] = b2s(a[2]); r[3] = b2s(a[3]);
  r[4] = b2s(b[0]); r[5] = b2s(b[1]); r[6] = b2s(b[2]); r[7] = b2s(b[3]);
  return r;
}

__device__ __forceinline__ float bf2f(short s) {
  return __uint_as_float(((unsigned)(unsigned short)s) << 16);
}

__device__ __forceinline__ float fast_tanh(float x) {
  float e;
  asm("v_exp_f32 %0, %1" : "=v"(e) : "v"(x * 2.88539008177792681f));  // 2^(2x/ln2)
  float r;
  asm("v_rcp_f32 %0, %1" : "=v"(r) : "v"(e + 1.0f));
  return 1.0f - 2.0f * r;
}

// k0: fragment-major repack of W_e (rows 512..1023 of W_attn):
// frag(h16, s) is ONE contiguous 1-KiB block; lane i loads base+i*16B.
__global__ __launch_bounds__(512) void k0_fragpack(const float* __restrict__ W,
                                                   unsigned short* __restrict__ WtF) {
  const int h16 = blockIdx.x;   // 0..31
  const int s = blockIdx.y;     // 0..15
  const int tid = threadIdx.x;  // 0..511
  const int lane = tid >> 3, e = tid & 7;
  const int lr = lane & 15, lq = lane >> 4;
  const int k = s * 32 + lq * 8 + e;
  const int h = h16 * 16 + lr;
  WtF[(size_t)(h16 * 16 + s) * 512 + tid] =
      (unsigned short)b2s(W[(size_t)(512 + k) * H_ + h]);
}

// k1: projb[b][h] = b_attn[h] + sum_e hidden[b][e] * W_attn[e][h]
__global__ __launch_bounds__(512) void k1_projb(const float* __restrict__ hidden,
                                                const float* __restrict__ W,
                                                const float* __restrict__ b_attn,
                                                float* __restrict__ projb) {
  __shared__ float hid_s[H_];
  __shared__ float part[4][128];
  const int b = blockIdx.x, hg = blockIdx.y;
  const int tid = threadIdx.x;
  const int hl = tid & 127, es = tid >> 7;
  hid_s[tid] = hidden[b * H_ + tid];
  __syncthreads();
  const int h = hg * 128 + hl;
  const float* wp = W + (size_t)(es * 128) * H_ + h;
  float s = 0.0f;
  #pragma unroll 8
  for (int e = 0; e < 128; ++e) s = fmaf(hid_s[es * 128 + e], wp[(size_t)e * H_], s);
  part[es][hl] = s;
  __syncthreads();
  if (es == 0)
    projb[b * H_ + h] = b_attn[h] + part[0][hl] + part[1][hl] + part[2][hl] + part[3][hl];
}

// k2: fused logits + chunk-softmax + partial context.
// 256 thr = 4 waves; block = 64T x 512H; wave tile 64T x 128H, acc[4][8]=128 AGPR.
// QUARTER-INTERLEAVED fill (R14 refined): prologue converts only chunks 0..15
// (16 KB exposed vs R14's 32 KB); batches 0..11 (chunks 16..63) load at step n,
// ds_write at step n+1 (parity reg pairs); 3 in-loop barriers at tops of steps
// 4/8/12 (after that quarter's last write). Otherwise zero-barrier drift loop.
// B from fragment-major WtF (coalesced 1-KiB frags), reg ping-pong, single aCur.
// Epilogue context reads the bf16 A tile from LDS; m_c via wave shfl-reduce.
__global__ __launch_bounds__(256, 2) void k2_logits(
    const float* __restrict__ enc, const unsigned short* __restrict__ wtF,
    const float* __restrict__ projb, const float* __restrict__ vw,
    float* __restrict__ logits, float* __restrict__ mstat,
    float* __restrict__ partial) {
  __shared__ unsigned short a_s[BM * 512];  // 64 KiB, whole-K A tile (bf16)
  __shared__ float projb_s[H_];
  __shared__ float vw_s[H_];
  __shared__ float part[BM][4];
  __shared__ float lg_s[BM];
  __shared__ float comb[3][64][8];  // 6 KiB, context combine

  const int b = blockIdx.y;
  const int chunk = blockIdx.x;
  const int t0 = chunk * BM;
  const int tid = threadIdx.x;
  const int lane = tid & 63;
  const int w = tid >> 6;  // wave id = H-slice (0..3)
  const int lr = lane & 15;
  const int lq = lane >> 4;

  projb_s[tid] = projb[b * H_ + tid];
  projb_s[tid + 256] = projb[b * H_ + tid + 256];
  vw_s[tid] = vw[tid];
  vw_s[tid + 256] = vw[tid + 256];

  const size_t row0 = (size_t)b * T_ + t0;

  // fill geometry: thread owns (row ra, slot ca); chunk = 16 B of bf16
  const int ra = tid >> 2, ca = tid & 3;
  const float* aSrc = enc + (row0 + ra) * (size_t)E_;
  unsigned short* aRow = &a_s[ra * 512];

  // ---- prologue: direct-fill quarter 0 (chunks 0..15) ----
  {
    f32x4 g[8];
    #pragma unroll
    for (int j = 0; j < 4; ++j) {
      const int c = ca + 4 * j;
      g[2 * j] = *(const f32x4*)(aSrc + c * 8);
      g[2 * j + 1] = *(const f32x4*)(aSrc + c * 8 + 4);
    }
    #pragma unroll
    for (int j = 0; j < 4; ++j) {
      const int c = ca + 4 * j;
      *(s16x8*)&aRow[(c ^ (ra & 7)) * 8] = cvt8(g[2 * j], g[2 * j + 1]);
    }
  }

  const int wu = __builtin_amdgcn_readfirstlane(w);
  const unsigned short* wtW = wtF + ((size_t)wu * 8 * 16) * 512 + (size_t)lane * 8;
  const unsigned short* aBase = &a_s[0];

#define LOADB(dst, s)                                                        \
  _Pragma("unroll") for (int nb = 0; nb < 8; ++nb) dst[nb] =                 \
      *(const s16x8*)(wtW + ((size_t)(nb * 16 + (s)) << 9));
#define LOADA(dst, s)                                                        \
  _Pragma("unroll") for (int a = 0; a < 4; ++a) dst[a] =                     \
      *(const s16x8*)&aBase[(a * 16 + lr) * 512 + (((s) * 4 + lq) ^ (lr & 7)) * 8];
#define MFMA32(af, bf)                                                       \
  __builtin_amdgcn_s_setprio(1);                                             \
  _Pragma("unroll") for (int a = 0; a < 4; ++a)                              \
  _Pragma("unroll") for (int nb = 0; nb < 8; ++nb) acc[a][nb] =              \
      __builtin_amdgcn_mfma_f32_16x16x32_bf16(af[a], bf[nb], acc[a][nb], 0, 0, 0); \
  __builtin_amdgcn_s_setprio(0);
// batch n (0..11) <-> chunks 16 + 4n + ca
#define LDFILL(dst, n)                                                       \
  {                                                                          \
    const int c_ = 16 + (n)*4 + ca;                                          \
    dst##0 = *(const f32x4*)(aSrc + c_ * 8);                                 \
    dst##1 = *(const f32x4*)(aSrc + c_ * 8 + 4);                             \
  }
#define WRFILL(src, n)                                                       \
  {                                                                          \
    const int c_ = 16 + (n)*4 + ca;                                          \
    *(s16x8*)&aRow[(c_ ^ (ra & 7)) * 8] = cvt8(src##0, src##1);              \
  }
#define QBARRIER                                                             \
  asm volatile("s_waitcnt lgkmcnt(0)" ::: "memory");                         \
  __builtin_amdgcn_s_barrier();                                              \
  __builtin_amdgcn_sched_barrier(0);

  f32x4 acc[4][8] = {};
  s16x8 bA[8], bB[8], aCur[4];
  f32x4 fE0, fE1, fO0, fO1;  // parity fill-reg pairs

  LOADB(bA, 0);
  __syncthreads();  // quarter 0 visible

  #pragma unroll
  for (int p = 0; p < 8; ++p) {
    const int s = 2 * p;
    // ======== even step s ========
    if (s >= 2 && s <= 12) WRFILL(fO, s - 1);      // odd batch s-1 (loaded at s-1)
    if (s == 4 || s == 8 || s == 12) { QBARRIER }  // quarter s/4 now readable
    if (s < 12) LDFILL(fE, s);                     // even batch s
    LOADB(bB, s + 1);
    LOADA(aCur, s);
    MFMA32(aCur, bA);
    // ======== odd step s+1 ========
    if (s < 12) WRFILL(fE, s);                     // even batch s (1-step distance)
    if (s + 1 < 12) LDFILL(fO, s + 1);             // odd batch s+1
    if (p < 7) LOADB(bA, s + 2);
    LOADA(aCur, s + 1);
    MFMA32(aCur, bB);
  }
#undef LOADA
#undef LOADB
#undef MFMA32
#undef LDFILL
#undef WRFILL
#undef QBARRIER

  // ---- logits: energy = tanh(acc + projb), partial = sum_h energy * vw ----
  #pragma unroll
  for (int a = 0; a < 4; ++a) {
    #pragma unroll
    for (int j = 0; j < 4; ++j) {
      float ssum = 0.0f;
      #pragma unroll
      for (int nb = 0; nb < 8; ++nb) {
        const int h = w * 128 + nb * 16 + lr;  // C/D: col = lane&15
        float x = acc[a][nb][j] + projb_s[h];
        ssum += fast_tanh(x) * vw_s[h];
      }
      ssum += __shfl_xor(ssum, 1);
      ssum += __shfl_xor(ssum, 2);
      ssum += __shfl_xor(ssum, 4);
      ssum += __shfl_xor(ssum, 8);
      if (lr == 0) part[a * 16 + lq * 4 + j][w] = ssum;  // C/D: row = lq*4+j
    }
  }
  __syncthreads();
  if (tid < BM) {
    float l = part[tid][0] + part[tid][1] + part[tid][2] + part[tid][3];
    lg_s[tid] = l;
    logits[(size_t)b * T_ + t0 + tid] = l;
  }
  __syncthreads();

  // ---- chunk softmax numerator + partial context from LDS bf16 A tile ----
  // m_c: one LDS read per lane + 6-level wave shfl-max (BM == 64 lanes)
  float m_c = lg_s[lane];
  #pragma unroll
  for (int d = 1; d < 64; d <<= 1) m_c = fmaxf(m_c, __shfl_xor(m_c, d));

  const int cc = tid & 63;  // bf16 chunk column (8 e-values)
  const int tg = tid >> 6;  // 0..3, 16 t-rows each
  float a8[8] = {};
  #pragma unroll 4
  for (int i = 0; i < 16; ++i) {
    const int r = tg * 16 + i;
    float pw = __expf(lg_s[r] - m_c);
    s16x8 av = *(const s16x8*)&a_s[r * 512 + (cc ^ (r & 7)) * 8];
    #pragma unroll
    for (int e = 0; e < 8; ++e) a8[e] = fmaf(pw, bf2f(av[e]), a8[e]);
  }
  if (tg > 0) {
    #pragma unroll
    for (int e = 0; e < 8; ++e) comb[tg - 1][cc][e] = a8[e];
  }
  __syncthreads();
  if (tg == 0) {
    float* pp = partial + ((size_t)(b * NCH + chunk)) * E_ + cc * 8;
    #pragma unroll
    for (int e = 0; e < 8; ++e)
      pp[e] = a8[e] + comb[0][cc][e] + comb[1][cc][e] + comb[2][cc][e];
    if (tid == 0) mstat[b * NCH + chunk] = m_c;
  }
}

// k3: softmax over T per batch -> weights; also per-b (max, Z)
__global__ __launch_bounds__(256) void k3_softmax(const float* __restrict__ logits,
                                                  float* __restrict__ weights,
                                                  float* __restrict__ mz) {
  __shared__ float red[4];
  const int b = blockIdx.x;
  const int tid = threadIdx.x;
  const float* lg = logits + (size_t)b * T_;
  float v[16];
  float m = -1e30f;
  #pragma unroll
  for (int i = 0; i < 16; ++i) {
    v[i] = lg[tid + i * 256];
    m = fmaxf(m, v[i]);
  }
  #pragma unroll
  for (int d = 1; d < 64; d <<= 1) m = fmaxf(m, __shfl_xor(m, d));
  if ((tid & 63) == 0) red[tid >> 6] = m;
  __syncthreads();
  m = fmaxf(fmaxf(red[0], red[1]), fmaxf(red[2], red[3]));
  __syncthreads();
  float s = 0.0f;
  #pragma unroll
  for (int i = 0; i < 16; ++i) {
    v[i] = __expf(v[i] - m);
    s += v[i];
  }
  #pragma unroll
  for (int d = 1; d < 64; d <<= 1) s += __shfl_xor(s, d);
  if ((tid & 63) == 0) red[tid >> 6] = s;
  __syncthreads();
  s = red[0] + red[1] + red[2] + red[3];
  float inv = 1.0f / s;
  #pragma unroll
  for (int i = 0; i < 16; ++i) weights[(size_t)b * T_ + tid + i * 256] = v[i] * inv;
  if (tid == 0) {
    mz[b * 2] = m;
    mz[b * 2 + 1] = s;
  }
}

// k5: context = sum_c exp(m_c - m_b) * partial[b,c,:] / Z_b
__global__ __launch_bounds__(128) void k5_ctx_final(const float* __restrict__ partial,
                                                    const float* __restrict__ mstat,
                                                    const float* __restrict__ mz,
                                                    float* __restrict__ ctx) {
  __shared__ float sc[NCH];
  const int b = blockIdx.x;
  const int tid = threadIdx.x;
  const float m_b = mz[b * 2];
  const float invZ = 1.0f / mz[b * 2 + 1];
  if (tid < NCH) sc[tid] = __expf(mstat[b * NCH + tid] - m_b);
  __syncthreads();
  const float* pp = partial + (size_t)b * NCH * E_ + tid * 4;
  f32x4 s = {};
  #pragma unroll 8
  for (int c = 0; c < NCH; ++c) s += sc[c] * (*(const f32x4*)(pp + (size_t)c * E_));
  s *= invZ;
  *(f32x4*)(ctx + (size_t)b * E_ + tid * 4) = s;
}

extern "C" void kernel_launch(void* const* d_in, const int* in_sizes, int n_in,
                              void* d_out, int out_size, void* d_ws, size_t ws_size,
                              hipStream_t stream) {
  const float* hidden = (const float*)d_in[0];
  const float* enc = (const float*)d_in[1];
  const float* W_attn = (const float*)d_in[2];
  const float* b_attn = (const float*)d_in[3];
  const float* v_w = (const float*)d_in[4];

  float* out_ctx = (float*)d_out;                  // 64*512
  float* out_w = (float*)d_out + (size_t)B_ * H_;  // 64*4096

  char* ws = (char*)d_ws;
  unsigned short* WtF = (unsigned short*)ws;     // 512 KiB (fragment-major)
  float* projb = (float*)(ws + (512 << 10));     // 128 KiB
  float* logits = (float*)(ws + (640 << 10));    // 1 MiB
  float* mstat = (float*)(ws + (1664 << 10));    // 16 KiB (64*64 chunk maxes)
  float* mz = (float*)(ws + (1700 << 10));       // 512 B  (per-b max, Z)
  float* partial = (float*)(ws + (1728 << 10));  // 8 MiB  (64*64*512 fp32)

  k0_fragpack<<<dim3(32, 16), 512, 0, stream>>>(W_attn, WtF);
  k1_projb<<<dim3(64, 4), 512, 0, stream>>>(hidden, W_attn, b_attn, projb);
  k2_logits<<<dim3(NCH, B_), 256, 0, stream>>>(enc, WtF, projb, v_w, logits, mstat, partial);
  k3_softmax<<<B_, 256, 0, stream>>>(logits, out_w, mz);
  k5_ctx_final<<<B_, 128, 0, stream>>>(partial, mstat, mz, out_ctx);
}

// Round 17
// 225.141 us; speedup vs baseline: 1.3918x; 1.0100x over previous
//
#include <hip/hip_runtime.h>
#include <hip/hip_bf16.h>

typedef __attribute__((ext_vector_type(4))) float f32x4;
typedef __attribute__((ext_vector_type(8))) short s16x8;

#define B_ 64
#define T_ 4096
#define H_ 512
#define E_ 512
#define BM 64          // T-rows per k2 block (= context chunk)
#define NCH (T_ / BM)  // 64 chunks per batch row

__device__ __forceinline__ short b2s(float x) {
  __hip_bfloat16 h = __float2bfloat16(x);  // RNE; pairs fuse to v_cvt_pk_bf16_f32
  return __builtin_bit_cast(short, h);
}

__device__ __forceinline__ s16x8 cvt8(f32x4 a, f32x4 b) {
  s16x8 r;
  r[0] = b2s(a[0]); r[1] = b2s(a[1]); r[2] = b2s(a[2]); r[3] = b2s(a[3]);
  r[4] = b2s(b[0]); r[5] = b2s(b[1]); r[6] = b2s(b[2]); r[7] = b2s(b[3]);
  return r;
}

__device__ __forceinline__ float bf2f(short s) {
  return __uint_as_float(((unsigned)(unsigned short)s) << 16);
}

__device__ __forceinline__ float fast_tanh(float x) {
  float e;
  asm("v_exp_f32 %0, %1" : "=v"(e) : "v"(x * 2.88539008177792681f));  // 2^(2x/ln2)
  float r;
  asm("v_rcp_f32 %0, %1" : "=v"(r) : "v"(e + 1.0f));
  return 1.0f - 2.0f * r;
}

// k01: fused {k0 fragment-major W_e repack} + {k1 projb GEMV}.
// blocks 0..511: WtF[frag(h16,s)] packing (1-KiB coalesced frags for k2).
// blocks 512..767: projb[b][h] = b_attn[h] + hidden[b]. @ W_h.
__global__ __launch_bounds__(512) void k01(const float* __restrict__ W,
                                           const float* __restrict__ hidden,
                                           const float* __restrict__ b_attn,
                                           unsigned short* __restrict__ WtF,
                                           float* __restrict__ projb) {
  __shared__ float hid_s[H_];
  __shared__ float part[4][128];
  const int bx = blockIdx.x;
  const int tid = threadIdx.x;
  if (bx < 512) {
    const int h16 = bx & 31;  // 0..31
    const int s = bx >> 5;    // 0..15
    const int lane = tid >> 3, e = tid & 7;
    const int lr = lane & 15, lq = lane >> 4;
    const int k = s * 32 + lq * 8 + e;
    const int h = h16 * 16 + lr;
    WtF[(size_t)(h16 * 16 + s) * 512 + tid] =
        (unsigned short)b2s(W[(size_t)(512 + k) * H_ + h]);
  } else {
    const int blk = bx - 512;
    const int b = blk & 63, hg = blk >> 6;
    const int hl = tid & 127, es = tid >> 7;
    hid_s[tid] = hidden[b * H_ + tid];
    __syncthreads();
    const int h = hg * 128 + hl;
    const float* wp = W + (size_t)(es * 128) * H_ + h;
    float s = 0.0f;
    #pragma unroll 8
    for (int e = 0; e < 128; ++e) s = fmaf(hid_s[es * 128 + e], wp[(size_t)e * H_], s);
    part[es][hl] = s;
    __syncthreads();
    if (es == 0)
      projb[b * H_ + h] = b_attn[h] + part[0][hl] + part[1][hl] + part[2][hl] + part[3][hl];
  }
}

// k2: fused logits + chunk-softmax + partial context.
// 256 thr = 4 waves; block = 64T x 512H; wave tile 64T x 128H, acc[4][8]=128 AGPR.
// QUARTER-INTERLEAVED fill: prologue converts only chunks 0..15; batches 0..11
// (chunks 16..63) load at step n, ds_write at step n+1 (parity reg pairs);
// 3 in-loop barriers at tops of steps 4/8/12. Otherwise zero-barrier drift loop.
// LOADA hoisted to step top so its LDS latency overlaps fill/LOADB issue.
// B from fragment-major WtF (coalesced 1-KiB frags), reg ping-pong, single aCur.
// Epilogue context reads the bf16 A tile from LDS; m_c via wave shfl-reduce.
__global__ __launch_bounds__(256, 2) void k2_logits(
    const float* __restrict__ enc, const unsigned short* __restrict__ wtF,
    const float* __restrict__ projb, const float* __restrict__ vw,
    float* __restrict__ logits, float* __restrict__ mstat,
    float* __restrict__ partial) {
  __shared__ unsigned short a_s[BM * 512];  // 64 KiB, whole-K A tile (bf16)
  __shared__ float projb_s[H_];
  __shared__ float vw_s[H_];
  __shared__ float part[BM][4];
  __shared__ float lg_s[BM];
  __shared__ float comb[3][64][8];  // 6 KiB, context combine

  const int b = blockIdx.y;
  const int chunk = blockIdx.x;
  const int t0 = chunk * BM;
  const int tid = threadIdx.x;
  const int lane = tid & 63;
  const int w = tid >> 6;  // wave id = H-slice (0..3)
  const int lr = lane & 15;
  const int lq = lane >> 4;

  projb_s[tid] = projb[b * H_ + tid];
  projb_s[tid + 256] = projb[b * H_ + tid + 256];
  vw_s[tid] = vw[tid];
  vw_s[tid + 256] = vw[tid + 256];

  const size_t row0 = (size_t)b * T_ + t0;

  // fill geometry: thread owns (row ra, slot ca); chunk = 16 B of bf16
  const int ra = tid >> 2, ca = tid & 3;
  const float* aSrc = enc + (row0 + ra) * (size_t)E_;
  unsigned short* aRow = &a_s[ra * 512];

  // ---- prologue: direct-fill quarter 0 (chunks 0..15) ----
  {
    f32x4 g[8];
    #pragma unroll
    for (int j = 0; j < 4; ++j) {
      const int c = ca + 4 * j;
      g[2 * j] = *(const f32x4*)(aSrc + c * 8);
      g[2 * j + 1] = *(const f32x4*)(aSrc + c * 8 + 4);
    }
    #pragma unroll
    for (int j = 0; j < 4; ++j) {
      const int c = ca + 4 * j;
      *(s16x8*)&aRow[(c ^ (ra & 7)) * 8] = cvt8(g[2 * j], g[2 * j + 1]);
    }
  }

  const int wu = __builtin_amdgcn_readfirstlane(w);
  const unsigned short* wtW = wtF + ((size_t)wu * 8 * 16) * 512 + (size_t)lane * 8;
  const unsigned short* aBase = &a_s[0];

#define LOADB(dst, s)                                                        \
  _Pragma("unroll") for (int nb = 0; nb < 8; ++nb) dst[nb] =                 \
      *(const s16x8*)(wtW + ((size_t)(nb * 16 + (s)) << 9));
#define LOADA(dst, s)                                                        \
  _Pragma("unroll") for (int a = 0; a < 4; ++a) dst[a] =                     \
      *(const s16x8*)&aBase[(a * 16 + lr) * 512 + (((s) * 4 + lq) ^ (lr & 7)) * 8];
#define MFMA32(af, bf)                                                       \
  __builtin_amdgcn_s_setprio(1);                                             \
  _Pragma("unroll") for (int a = 0; a < 4; ++a)                              \
  _Pragma("unroll") for (int nb = 0; nb < 8; ++nb) acc[a][nb] =              \
      __builtin_amdgcn_mfma_f32_16x16x32_bf16(af[a], bf[nb], acc[a][nb], 0, 0, 0); \
  __builtin_amdgcn_s_setprio(0);
// batch n (0..11) <-> chunks 16 + 4n + ca
#define LDFILL(dst, n)                                                       \
  {                                                                          \
    const int c_ = 16 + (n)*4 + ca;                                          \
    dst##0 = *(const f32x4*)(aSrc + c_ * 8);                                 \
    dst##1 = *(const f32x4*)(aSrc + c_ * 8 + 4);                             \
  }
#define WRFILL(src, n)                                                       \
  {                                                                          \
    const int c_ = 16 + (n)*4 + ca;                                          \
    *(s16x8*)&aRow[(c_ ^ (ra & 7)) * 8] = cvt8(src##0, src##1);              \
  }
#define QBARRIER                                                             \
  asm volatile("s_waitcnt lgkmcnt(0)" ::: "memory");                         \
  __builtin_amdgcn_s_barrier();                                              \
  __builtin_amdgcn_sched_barrier(0);

  f32x4 acc[4][8] = {};
  s16x8 bA[8], bB[8], aCur[4];
  f32x4 fE0, fE1, fO0, fO1;  // parity fill-reg pairs

  LOADB(bA, 0);
  __syncthreads();  // quarter 0 visible

  #pragma unroll
  for (int p = 0; p < 8; ++p) {
    const int s = 2 * p;
    // ======== even step s ========
    if (s == 4 || s == 8 || s == 12) {
      WRFILL(fO, s - 1);  // odd batch s-1 (loaded at step s-1)
      QBARRIER            // quarter s/4 now readable by all waves
      LOADA(aCur, s);
    } else {
      LOADA(aCur, s);  // issue LDS reads first: latency overlaps issue below
      if (s >= 2 && s <= 12) WRFILL(fO, s - 1);
    }
    if (s < 12) LDFILL(fE, s);  // even batch s
    LOADB(bB, s + 1);
    MFMA32(aCur, bA);
    // ======== odd step s+1 ========
    LOADA(aCur, s + 1);  // quarter (s+1)>>2 visible since its barrier
    if (s < 12) WRFILL(fE, s);
    if (s + 1 < 12) LDFILL(fO, s + 1);
    if (p < 7) LOADB(bA, s + 2);
    MFMA32(aCur, bB);
  }
#undef LOADA
#undef LOADB
#undef MFMA32
#undef LDFILL
#undef WRFILL
#undef QBARRIER

  // ---- logits: energy = tanh(acc + projb), partial = sum_h energy * vw ----
  #pragma unroll
  for (int a = 0; a < 4; ++a) {
    #pragma unroll
    for (int j = 0; j < 4; ++j) {
      float ssum = 0.0f;
      #pragma unroll
      for (int nb = 0; nb < 8; ++nb) {
        const int h = w * 128 + nb * 16 + lr;  // C/D: col = lane&15
        float x = acc[a][nb][j] + projb_s[h];
        ssum += fast_tanh(x) * vw_s[h];
      }
      ssum += __shfl_xor(ssum, 1);
      ssum += __shfl_xor(ssum, 2);
      ssum += __shfl_xor(ssum, 4);
      ssum += __shfl_xor(ssum, 8);
      if (lr == 0) part[a * 16 + lq * 4 + j][w] = ssum;  // C/D: row = lq*4+j
    }
  }
  __syncthreads();
  if (tid < BM) {
    float l = part[tid][0] + part[tid][1] + part[tid][2] + part[tid][3];
    lg_s[tid] = l;
    logits[(size_t)b * T_ + t0 + tid] = l;
  }
  __syncthreads();

  // ---- chunk softmax numerator + partial context from LDS bf16 A tile ----
  // m_c: one LDS read per lane + 6-level wave shfl-max (BM == 64 lanes)
  float m_c = lg_s[lane];
  #pragma unroll
  for (int d = 1; d < 64; d <<= 1) m_c = fmaxf(m_c, __shfl_xor(m_c, d));

  const int cc = tid & 63;  // bf16 chunk column (8 e-values)
  const int tg = tid >> 6;  // 0..3, 16 t-rows each
  float a8[8] = {};
  #pragma unroll 4
  for (int i = 0; i < 16; ++i) {
    const int r = tg * 16 + i;
    float pw = __expf(lg_s[r] - m_c);
    s16x8 av = *(const s16x8*)&a_s[r * 512 + (cc ^ (r & 7)) * 8];
    #pragma unroll
    for (int e = 0; e < 8; ++e) a8[e] = fmaf(pw, bf2f(av[e]), a8[e]);
  }
  if (tg > 0) {
    #pragma unroll
    for (int e = 0; e < 8; ++e) comb[tg - 1][cc][e] = a8[e];
  }
  __syncthreads();
  if (tg == 0) {
    float* pp = partial + ((size_t)(b * NCH + chunk)) * E_ + cc * 8;
    #pragma unroll
    for (int e = 0; e < 8; ++e)
      pp[e] = a8[e] + comb[0][cc][e] + comb[1][cc][e] + comb[2][cc][e];
    if (tid == 0) mstat[b * NCH + chunk] = m_c;
  }
}

// k35: fused {k3 softmax -> weights} + {k5 context reduce}.
// One block per b; m and Z stay in registers between the phases (no mz ws).
__global__ __launch_bounds__(256) void k35(const float* __restrict__ logits,
                                           const float* __restrict__ mstat,
                                           const float* __restrict__ partial,
                                           float* __restrict__ weights,
                                           float* __restrict__ ctx) {
  __shared__ float red[4];
  __shared__ float sc[NCH];
  const int b = blockIdx.x;
  const int tid = threadIdx.x;
  const float* lg = logits + (size_t)b * T_;
  float v[16];
  float m = -1e30f;
  #pragma unroll
  for (int i = 0; i < 16; ++i) {
    v[i] = lg[tid + i * 256];
    m = fmaxf(m, v[i]);
  }
  #pragma unroll
  for (int d = 1; d < 64; d <<= 1) m = fmaxf(m, __shfl_xor(m, d));
  if ((tid & 63) == 0) red[tid >> 6] = m;
  __syncthreads();
  m = fmaxf(fmaxf(red[0], red[1]), fmaxf(red[2], red[3]));
  __syncthreads();
  float s = 0.0f;
  #pragma unroll
  for (int i = 0; i < 16; ++i) {
    v[i] = __expf(v[i] - m);
    s += v[i];
  }
  #pragma unroll
  for (int d = 1; d < 64; d <<= 1) s += __shfl_xor(s, d);
  if ((tid & 63) == 0) red[tid >> 6] = s;
  __syncthreads();
  s = red[0] + red[1] + red[2] + red[3];
  const float inv = 1.0f / s;
  #pragma unroll
  for (int i = 0; i < 16; ++i) weights[(size_t)b * T_ + tid + i * 256] = v[i] * inv;

  // phase 2: context = sum_c exp(m_c - m) * partial[b,c,:] * inv
  if (tid < NCH) sc[tid] = __expf(mstat[b * NCH + tid] - m);
  __syncthreads();
  const float* pp = partial + (size_t)b * NCH * E_ + tid * 2;
  float c0 = 0.0f, c1 = 0.0f;
  #pragma unroll 8
  for (int c = 0; c < NCH; ++c) {
    float2 pv = *(const float2*)(pp + (size_t)c * E_);
    c0 = fmaf(sc[c], pv.x, c0);
    c1 = fmaf(sc[c], pv.y, c1);
  }
  float2 r = {c0 * inv, c1 * inv};
  *(float2*)(ctx + (size_t)b * E_ + tid * 2) = r;
}

extern "C" void kernel_launch(void* const* d_in, const int* in_sizes, int n_in,
                              void* d_out, int out_size, void* d_ws, size_t ws_size,
                              hipStream_t stream) {
  const float* hidden = (const float*)d_in[0];
  const float* enc = (const float*)d_in[1];
  const float* W_attn = (const float*)d_in[2];
  const float* b_attn = (const float*)d_in[3];
  const float* v_w = (const float*)d_in[4];

  float* out_ctx = (float*)d_out;                  // 64*512
  float* out_w = (float*)d_out + (size_t)B_ * H_;  // 64*4096

  char* ws = (char*)d_ws;
  unsigned short* WtF = (unsigned short*)ws;     // 512 KiB (fragment-major)
  float* projb = (float*)(ws + (512 << 10));     // 128 KiB
  float* logits = (float*)(ws + (640 << 10));    // 1 MiB
  float* mstat = (float*)(ws + (1664 << 10));    // 16 KiB (64*64 chunk maxes)
  float* partial = (float*)(ws + (1728 << 10));  // 8 MiB  (64*64*512 fp32)

  k01<<<768, 512, 0, stream>>>(W_attn, hidden, b_attn, WtF, projb);
  k2_logits<<<dim3(NCH, B_), 256, 0, stream>>>(enc, WtF, projb, v_w, logits, mstat, partial);
  k35<<<B_, 256, 0, stream>>>(logits, mstat, partial, out_w, out_ctx);
}